// Round 8
// baseline (564.521 us; speedup 1.0000x reference)
//
#include <hip/hip_runtime.h>
#include <hip/hip_bf16.h>

#define N_NODES 100000
#define N_HEDGES 20000
#define N_EDGES 800000
#define HSEG (2 * N_HEDGES)            // 40000 hedge segments (t,h)
#define NSEG (2 * N_NODES)             // 200000 node segments (t,n)
#define MSEG (HSEG + NSEG)             // 240000 segments
#define NSUB 8                          // XCD-private sub-lists (blockIdx&7)
#define TOT (NSUB * MSEG)               // 1,920,000 counters
#define SCAN_BLOCKS ((TOT + 2047) / 2048)  // 938

typedef __hip_bfloat16 bf16;
typedef __attribute__((ext_vector_type(8))) short bf16x8;
typedef __attribute__((ext_vector_type(4))) float f32x4;

__device__ __forceinline__ float b2f(bf16 v) { return __bfloat162float(v); }
__device__ __forceinline__ bf16 f2b(float v) { return __float2bfloat16(v); }
__device__ __forceinline__ short f2s(float v) {
    bf16 b = __float2bfloat16(v);
    return *reinterpret_cast<short*>(&b);
}
__device__ __forceinline__ bf16x8 pack8(float4 a, float4 b) {
    bf16x8 r = {f2s(a.x), f2s(a.y), f2s(a.z), f2s(a.w),
                f2s(b.x), f2s(b.y), f2s(b.z), f2s(b.w)};
    return r;
}

// ---------------------------------------------------------------------------
// MFMA conv: xl[t] = x @ W_conv[t], one wave per 16-row tile, both types.
// ---------------------------------------------------------------------------
__global__ __launch_bounds__(256) void k_conv(const float* __restrict__ x,
                                              const float* __restrict__ Wc,
                                              bf16* __restrict__ xl) {
    __shared__ bf16 Wpk[2 * 2 * 4 * 64 * 8];  // 16 KB
    for (int i = threadIdx.x; i < 2 * 2 * 4 * 64 * 8; i += 256) {
        int j = i & 7;
        int ln = (i >> 3) & 63;
        int r2 = i >> 9;
        int ct = r2 & 3;
        int kt = (r2 >> 2) & 1;
        int t = r2 >> 3;
        int k = kt * 32 + ((ln >> 4) << 3) + j;
        int n = ct * 16 + (ln & 15);
        Wpk[i] = f2b(Wc[((size_t)t * 64 + k) * 64 + n]);
    }
    __syncthreads();
    int wid = threadIdx.x >> 6, lane = threadIdx.x & 63;
    int quad = lane >> 4, l16 = lane & 15;
    int wave = blockIdx.x * 4 + wid, n_waves = gridDim.x * 4;
    const f32x4 zero = {0.f, 0.f, 0.f, 0.f};
    for (int tile = wave; tile < N_NODES / 16; tile += n_waves) {
        int row0 = tile * 16;
        const float* xp = x + (size_t)(row0 + l16) * 64 + quad * 8;
        bf16x8 a0 = pack8(*(const float4*)xp, *(const float4*)(xp + 4));
        bf16x8 a1 = pack8(*(const float4*)(xp + 32), *(const float4*)(xp + 36));
#define LDBC(t, kt, ct) (*(const bf16x8*)&Wpk[((((t)*2 + (kt)) * 4 + (ct)) * 64 + lane) * 8])
#pragma unroll
        for (int t = 0; t < 2; ++t) {
#pragma unroll
            for (int ct = 0; ct < 4; ++ct) {
                f32x4 acc = __builtin_amdgcn_mfma_f32_16x16x32_bf16(a0, LDBC(t, 0, ct), zero, 0, 0, 0);
                acc = __builtin_amdgcn_mfma_f32_16x16x32_bf16(a1, LDBC(t, 1, ct), acc, 0, 0, 0);
#pragma unroll
                for (int rg = 0; rg < 4; ++rg) {
                    int row = row0 + quad * 4 + rg;
                    xl[(size_t)t * N_NODES * 64 + (size_t)row * 64 + ct * 16 + l16] = f2b(acc[rg]);
                }
            }
        }
#undef LDBC
    }
}

// ---------------------------------------------------------------------------
// Histogram into XCD-private counters cnt[sub][seg], sub = blockIdx&7.
// ---------------------------------------------------------------------------
__global__ __launch_bounds__(256) void k_hist(const int* __restrict__ node_idx,
                                              const int* __restrict__ hedge_idx,
                                              const int* __restrict__ attr,
                                              int* __restrict__ cnt) {
    int e = blockIdx.x * 256 + threadIdx.x;
    int base = (blockIdx.x & (NSUB - 1)) * MSEG;
    if (e < N_EDGES) {
        int t = attr[e];
        atomicAdd(&cnt[base + t * N_HEDGES + hedge_idx[e]], 1);
        atomicAdd(&cnt[base + HSEG + t * N_NODES + node_idx[e]], 1);
    }
}

// ---------------------------------------------------------------------------
// Scan 1/3: 2048 elems/block (256 thr x 8), partial exclusive scan + bsum.
// ---------------------------------------------------------------------------
__global__ __launch_bounds__(256) void k_scan1(const int* __restrict__ cnt,
                                               int* __restrict__ off,
                                               int* __restrict__ bsum) {
    __shared__ int s[256];
    int base = blockIdx.x * 2048 + threadIdx.x * 8;
    int v[8];
    int tsum = 0;
#pragma unroll
    for (int j = 0; j < 8; ++j) {
        int g = base + j;
        v[j] = (g < TOT) ? cnt[g] : 0;
        tsum += v[j];
    }
    s[threadIdx.x] = tsum;
    __syncthreads();
    for (int o = 1; o < 256; o <<= 1) {
        int t = (threadIdx.x >= o) ? s[threadIdx.x - o] : 0;
        __syncthreads();
        s[threadIdx.x] += t;
        __syncthreads();
    }
    int run = s[threadIdx.x] - tsum;
#pragma unroll
    for (int j = 0; j < 8; ++j) {
        int g = base + j;
        if (g < TOT) off[g] = run;
        run += v[j];
    }
    if (threadIdx.x == 255) bsum[blockIdx.x] = s[255];
}

// ---------------------------------------------------------------------------
// Scan 2/3: exclusive scan of SCAN_BLOCKS (<=1024) block sums, one block.
// ---------------------------------------------------------------------------
__global__ __launch_bounds__(1024) void k_scan2(int* __restrict__ bsum) {
    __shared__ int s[1024];
    int tid = threadIdx.x;
    int v = (tid < SCAN_BLOCKS) ? bsum[tid] : 0;
    s[tid] = v;
    __syncthreads();
    for (int o = 1; o < 1024; o <<= 1) {
        int t = (tid >= o) ? s[tid - o] : 0;
        __syncthreads();
        s[tid] += t;
        __syncthreads();
    }
    if (tid < SCAN_BLOCKS) bsum[tid] = s[tid] - v;
}

// ---------------------------------------------------------------------------
// Scan 3/3: final off + cursor copy + TRANSPOSED offsets offT[seg][8]
// (so consumers load a segment's 8 sub-begs with 2 int4 broadcast loads;
// ends = offT[seg+1]). Sentinel row offT[MSEG][k] = off[(k+1)*MSEG].
// ---------------------------------------------------------------------------
__global__ __launch_bounds__(256) void k_scan3(int* __restrict__ off,
                                               const int* __restrict__ bsum,
                                               int* __restrict__ cursor,
                                               int* __restrict__ offT) {
    int base = blockIdx.x * 2048 + threadIdx.x * 8;
    int add = bsum[blockIdx.x];
#pragma unroll
    for (int j = 0; j < 8; ++j) {
        int g = base + j;
        if (g < TOT) {
            int v = off[g] + add;
            off[g] = v;
            cursor[g] = v;
            int k = g / MSEG, s = g - k * MSEG;
            offT[s * NSUB + k] = v;
            if (s == 0 && k > 0) offT[MSEG * NSUB + (k - 1)] = v;  // end of sub k-1
        }
    }
    if (base == 0) offT[MSEG * NSUB + 7] = 2 * N_EDGES;
}

// ---------------------------------------------------------------------------
// Scatter into XCD-private sub-lists (sub = blockIdx&7).
// ---------------------------------------------------------------------------
__global__ __launch_bounds__(256) void k_scatter(const int* __restrict__ node_idx,
                                                 const int* __restrict__ hedge_idx,
                                                 const int* __restrict__ attr,
                                                 int* __restrict__ cursor,
                                                 int* __restrict__ sortedAll) {
    int e = blockIdx.x * 256 + threadIdx.x;
    int base = (blockIdx.x & (NSUB - 1)) * MSEG;
    if (e < N_EDGES) {
        int t = attr[e], n = node_idx[e], h = hedge_idx[e];
        int p1 = atomicAdd(&cursor[base + t * N_HEDGES + h], 1);
        sortedAll[p1] = t * N_NODES + n;
        int p2 = atomicAdd(&cursor[base + HSEG + t * N_NODES + n], 1);
        sortedAll[p2] = t * N_HEDGES + h;
    }
}

// ---------------------------------------------------------------------------
// Segment gather-reduce, round-robin over the 8 sub-lists: each round issues
// up to 8 INDEPENDENT idx->row gather chains (prev version ran 8 sequential
// mini-loops + 16 serial offset loads -> latency-bound, 142us on node side).
// ---------------------------------------------------------------------------
__device__ __forceinline__ float seg_gather(const int* __restrict__ offT,
                                            const int* __restrict__ sortedAll,
                                            const bf16* __restrict__ rows,
                                            int s, int lane, int* total) {
    int4 b0 = *(const int4*)&offT[s * NSUB];
    int4 b1 = *(const int4*)&offT[s * NSUB + 4];
    int4 e0 = *(const int4*)&offT[(s + 1) * NSUB];
    int4 e1 = *(const int4*)&offT[(s + 1) * NSUB + 4];
    int beg[8] = {b0.x, b0.y, b0.z, b0.w, b1.x, b1.y, b1.z, b1.w};
    int c[8] = {e0.x - b0.x, e0.y - b0.y, e0.z - b0.z, e0.w - b0.w,
                e1.x - b1.x, e1.y - b1.y, e1.z - b1.z, e1.w - b1.w};
    int cmax = 0, tot = 0;
#pragma unroll
    for (int k = 0; k < NSUB; ++k) {
        cmax = max(cmax, c[k]);
        tot += c[k];
    }
    float sum = 0.f;
    for (int r = 0; r < cmax; ++r) {
#pragma unroll
        for (int k = 0; k < NSUB; ++k) {
            if (r < c[k]) {  // wave-uniform branch
                int idx = sortedAll[beg[k] + r];
                sum += b2f(rows[(size_t)idx * 64 + lane]);
            }
        }
    }
    *total = tot;
    return sum;
}

// CSR node->hedge: ef[t][h] = (1/B) * sum xl rows.
__global__ __launch_bounds__(256) void k_ef2(const int* __restrict__ offT,
                                             const int* __restrict__ sortedAll,
                                             const bf16* __restrict__ xl,
                                             bf16* __restrict__ ef16) {
    int wid = threadIdx.x >> 6, lane = threadIdx.x & 63;
    int s = blockIdx.x * 4 + wid;
    if (s >= HSEG) return;
    int c;
    float sum = seg_gather(offT, sortedAll, xl, s, lane, &c);
    float scale = c > 0 ? 1.0f / (float)c : 0.f;
    ef16[(size_t)s * 64 + lane] = f2b(sum * scale);
}

// CSR hedge->node: mixin[t][n] = (1/D) * sum ef rows + b_conv[t].
__global__ __launch_bounds__(256) void k_no2(const int* __restrict__ offT,
                                             const int* __restrict__ sortedAll,
                                             const bf16* __restrict__ ef16,
                                             const float* __restrict__ bconv,
                                             bf16* __restrict__ mixin16) {
    int wid = threadIdx.x >> 6, lane = threadIdx.x & 63;
    int j = blockIdx.x * 4 + wid;
    if (j >= NSEG) return;
    int c;
    float sum = seg_gather(offT, sortedAll, ef16, HSEG + j, lane, &c);
    float scale = c > 0 ? 1.0f / (float)c : 0.f;
    int t = j / N_NODES;
    float bc = bconv[t * 64 + lane];
    mixin16[(size_t)j * 64 + lane] = f2b(sum * scale + bc);
}

// ---------------------------------------------------------------------------
// MFMA mix: h = relu(mixin @ W_mix + b_mix), bf16 out. K=128 (4 k-frags).
// ---------------------------------------------------------------------------
__global__ __launch_bounds__(256) void k_mix(const bf16* __restrict__ mixin16,
                                             const float* __restrict__ Wm_g,
                                             const float* __restrict__ bm_g,
                                             bf16* __restrict__ hbuf16) {
    __shared__ bf16 Wpk[4 * 4 * 64 * 8];  // 16 KB
    for (int i = threadIdx.x; i < 4 * 4 * 64 * 8; i += 256) {
        int j = i & 7;
        int ln = (i >> 3) & 63;
        int r2 = i >> 9;
        int ct = r2 & 3;
        int kt = r2 >> 2;
        int k = kt * 32 + ((ln >> 4) << 3) + j;
        int n = ct * 16 + (ln & 15);
        Wpk[i] = f2b(Wm_g[(size_t)k * 64 + n]);
    }
    __syncthreads();
    int wid = threadIdx.x >> 6, lane = threadIdx.x & 63;
    int quad = lane >> 4, l16 = lane & 15;
    float bmv[4];
#pragma unroll
    for (int ct = 0; ct < 4; ++ct) bmv[ct] = bm_g[ct * 16 + l16];

    int wave = blockIdx.x * 4 + wid, n_waves = gridDim.x * 4;
    for (int tile = wave; tile < N_NODES / 16; tile += n_waves) {
        int row0 = tile * 16;
        int arow = row0 + l16;
        bf16x8 af[4];
#pragma unroll
        for (int kt = 0; kt < 4; ++kt) {
            const bf16* src = (kt < 2)
                ? mixin16 + (size_t)arow * 64 + kt * 32 + quad * 8
                : mixin16 + ((size_t)N_NODES + arow) * 64 + (kt - 2) * 32 + quad * 8;
            af[kt] = *(const bf16x8*)src;
        }
#define LDBM(kt, ct) (*(const bf16x8*)&Wpk[(((kt)*4 + (ct)) * 64 + lane) * 8])
#pragma unroll
        for (int ct = 0; ct < 4; ++ct) {
            f32x4 acc = {bmv[ct], bmv[ct], bmv[ct], bmv[ct]};
#pragma unroll
            for (int kt = 0; kt < 4; ++kt)
                acc = __builtin_amdgcn_mfma_f32_16x16x32_bf16(af[kt], LDBM(kt, ct), acc, 0, 0, 0);
#pragma unroll
            for (int rg = 0; rg < 4; ++rg) {
                int row = row0 + quad * 4 + rg;
                hbuf16[(size_t)row * 64 + ct * 16 + l16] = f2b(fmaxf(acc[rg], 0.f));
            }
        }
#undef LDBM
    }
}

// ---------------------------------------------------------------------------
// MFMA GRU: one wave per 16-row tile; h_prev cast fp32->bf16 inline.
// ---------------------------------------------------------------------------
#define GRU_TILES (N_NODES / 16)
__global__ __launch_bounds__(256) void k_gru(const bf16* __restrict__ hbuf16,
                                             const float* __restrict__ h_prev,
                                             const float* __restrict__ Wih_g,
                                             const float* __restrict__ Whh_g,
                                             const float* __restrict__ bih_g,
                                             const float* __restrict__ bhh_g,
                                             const float* __restrict__ Wro_g,
                                             const float* __restrict__ bro_g,
                                             float* __restrict__ out_h,
                                             float* __restrict__ out_o) {
    __shared__ bf16 Wpk[2 * 2 * 12 * 64 * 8];  // 48 KB
    for (int i = threadIdx.x; i < 2 * 2 * 12 * 64 * 8; i += 256) {
        int j = i & 7;
        int r = i >> 3;
        int ln = r & 63;
        int r2 = r >> 6;
        int ct = r2 % 12;
        int r3 = r2 / 12;
        int kt = r3 & 1;
        int mat = r3 >> 1;
        int k = kt * 32 + ((ln >> 4) << 3) + j;
        int n = ct * 16 + (ln & 15);
        float v = mat == 0 ? Wih_g[k * 192 + n] : Whh_g[k * 192 + n];
        Wpk[i] = f2b(v);
    }
    __syncthreads();

    int wid = threadIdx.x >> 6, lane = threadIdx.x & 63;
    int quad = lane >> 4, l16 = lane & 15;

    float bi[3][4], bh[3][4], wv[4][3];
    for (int g = 0; g < 3; ++g)
        for (int cc = 0; cc < 4; ++cc) {
            bi[g][cc] = bih_g[g * 64 + cc * 16 + l16];
            bh[g][cc] = bhh_g[g * 64 + cc * 16 + l16];
        }
    for (int cc = 0; cc < 4; ++cc)
        for (int c = 0; c < 3; ++c)
            wv[cc][c] = Wro_g[(cc * 16 + l16) * 64 + c];
    float bro0 = bro_g[0], bro1 = bro_g[1], bro2 = bro_g[2];

    int wave = blockIdx.x * 4 + wid;
    int n_waves = gridDim.x * 4;
    const f32x4 zero = {0.f, 0.f, 0.f, 0.f};

    for (int tile = wave; tile < GRU_TILES; tile += n_waves) {
        int row0 = tile * 16;
        const bf16* ha_p = hbuf16 + (size_t)(row0 + l16) * 64 + quad * 8;
        bf16x8 ha0 = *(const bf16x8*)ha_p;
        bf16x8 ha1 = *(const bf16x8*)(ha_p + 32);
        const float* pp = h_prev + (size_t)(row0 + l16) * 64 + quad * 8;
        bf16x8 pa0 = pack8(*(const float4*)pp, *(const float4*)(pp + 4));
        bf16x8 pa1 = pack8(*(const float4*)(pp + 32), *(const float4*)(pp + 36));

        float p[4][3];
#pragma unroll
        for (int rg = 0; rg < 4; ++rg) p[rg][0] = p[rg][1] = p[rg][2] = 0.f;

#pragma unroll
        for (int cc = 0; cc < 4; ++cc) {
#define LDB(mat, kt, ct) (*(const bf16x8*)&Wpk[((((mat)*2 + (kt)) * 12 + (ct)) * 64 + lane) * 8])
            f32x4 gir = __builtin_amdgcn_mfma_f32_16x16x32_bf16(ha0, LDB(0, 0, cc), zero, 0, 0, 0);
            gir = __builtin_amdgcn_mfma_f32_16x16x32_bf16(ha1, LDB(0, 1, cc), gir, 0, 0, 0);
            f32x4 giz = __builtin_amdgcn_mfma_f32_16x16x32_bf16(ha0, LDB(0, 0, cc + 4), zero, 0, 0, 0);
            giz = __builtin_amdgcn_mfma_f32_16x16x32_bf16(ha1, LDB(0, 1, cc + 4), giz, 0, 0, 0);
            f32x4 gin = __builtin_amdgcn_mfma_f32_16x16x32_bf16(ha0, LDB(0, 0, cc + 8), zero, 0, 0, 0);
            gin = __builtin_amdgcn_mfma_f32_16x16x32_bf16(ha1, LDB(0, 1, cc + 8), gin, 0, 0, 0);
            f32x4 ghr = __builtin_amdgcn_mfma_f32_16x16x32_bf16(pa0, LDB(1, 0, cc), zero, 0, 0, 0);
            ghr = __builtin_amdgcn_mfma_f32_16x16x32_bf16(pa1, LDB(1, 1, cc), ghr, 0, 0, 0);
            f32x4 ghz = __builtin_amdgcn_mfma_f32_16x16x32_bf16(pa0, LDB(1, 0, cc + 4), zero, 0, 0, 0);
            ghz = __builtin_amdgcn_mfma_f32_16x16x32_bf16(pa1, LDB(1, 1, cc + 4), ghz, 0, 0, 0);
            f32x4 ghn = __builtin_amdgcn_mfma_f32_16x16x32_bf16(pa0, LDB(1, 0, cc + 8), zero, 0, 0, 0);
            ghn = __builtin_amdgcn_mfma_f32_16x16x32_bf16(pa1, LDB(1, 1, cc + 8), ghn, 0, 0, 0);
#undef LDB
#pragma unroll
            for (int rg = 0; rg < 4; ++rg) {
                int row = row0 + quad * 4 + rg;
                float pv = h_prev[(size_t)row * 64 + cc * 16 + l16];
                float rr = 1.f / (1.f + __expf(-(gir[rg] + bi[0][cc] + ghr[rg] + bh[0][cc])));
                float zz = 1.f / (1.f + __expf(-(giz[rg] + bi[1][cc] + ghz[rg] + bh[1][cc])));
                float nn = tanhf(gin[rg] + bi[2][cc] + rr * (ghn[rg] + bh[2][cc]));
                float hn = (1.f - zz) * nn + zz * pv;
                out_h[(size_t)row * 64 + cc * 16 + l16] = hn;
                p[rg][0] += hn * wv[cc][0];
                p[rg][1] += hn * wv[cc][1];
                p[rg][2] += hn * wv[cc][2];
            }
        }
#pragma unroll
        for (int rg = 0; rg < 4; ++rg) {
#pragma unroll
            for (int m = 1; m < 16; m <<= 1) {
                p[rg][0] += __shfl_xor(p[rg][0], m);
                p[rg][1] += __shfl_xor(p[rg][1], m);
                p[rg][2] += __shfl_xor(p[rg][2], m);
            }
        }
        if (l16 == 0) {
#pragma unroll
            for (int rg = 0; rg < 4; ++rg) {
                int row = row0 + quad * 4 + rg;
                out_o[(size_t)row * 3 + 0] = p[rg][0] + bro0;
                out_o[(size_t)row * 3 + 1] = p[rg][1] + bro1;
                out_o[(size_t)row * 3 + 2] = p[rg][2] + bro2;
            }
        }
    }
}

extern "C" void kernel_launch(void* const* d_in, const int* in_sizes, int n_in,
                              void* d_out, int out_size, void* d_ws, size_t ws_size,
                              hipStream_t stream) {
    const float* x        = (const float*)d_in[0];
    const float* h_prev   = (const float*)d_in[1];
    const int* node_idx   = (const int*)d_in[2];
    const int* hedge_idx  = (const int*)d_in[3];
    const int* edge_attr  = (const int*)d_in[4];
    const float* W_conv   = (const float*)d_in[5];
    const float* b_conv   = (const float*)d_in[6];
    const float* W_mix    = (const float*)d_in[7];
    const float* b_mix    = (const float*)d_in[8];
    const float* W_ih     = (const float*)d_in[9];
    const float* W_hh     = (const float*)d_in[10];
    const float* b_ih     = (const float*)d_in[11];
    const float* b_hh     = (const float*)d_in[12];
    const float* W_ro     = (const float*)d_in[13];
    const float* b_ro     = (const float*)d_in[14];

    char* p = (char*)d_ws;
    auto alloc = [&](size_t bytes) {
        char* r = p;
        p += (bytes + 63) & ~(size_t)63;
        return r;
    };
    int* cnt       = (int*)alloc((size_t)TOT * 4);        // [zeroed]
    int* off       = (int*)alloc((size_t)(TOT + 1) * 4);
    int* cursor    = (int*)alloc((size_t)TOT * 4);
    int* offT      = (int*)alloc((size_t)(MSEG + 1) * NSUB * 4);
    int* bsum      = (int*)alloc(1024 * 4);
    int* sortedAll = (int*)alloc((size_t)2 * N_EDGES * 4);
    bf16* xl       = (bf16*)alloc((size_t)2 * N_NODES * 64 * 2);
    bf16* ef16     = (bf16*)alloc((size_t)HSEG * 64 * 2);
    bf16* hbuf16   = (bf16*)alloc((size_t)N_NODES * 64 * 2);
    bf16* mixin16  = xl;  // alias: xl dead after k_ef2

    hipMemsetAsync(cnt, 0, (size_t)TOT * 4, stream);

    float* out_h = (float*)d_out;
    float* out_o = out_h + (size_t)N_NODES * 64;

    k_conv<<<512, 256, 0, stream>>>(x, W_conv, xl);
    k_hist<<<(N_EDGES + 255) / 256, 256, 0, stream>>>(node_idx, hedge_idx, edge_attr, cnt);
    k_scan1<<<SCAN_BLOCKS, 256, 0, stream>>>(cnt, off, bsum);
    k_scan2<<<1, 1024, 0, stream>>>(bsum);
    k_scan3<<<SCAN_BLOCKS, 256, 0, stream>>>(off, bsum, cursor, offT);
    k_scatter<<<(N_EDGES + 255) / 256, 256, 0, stream>>>(node_idx, hedge_idx, edge_attr,
                                                         cursor, sortedAll);
    k_ef2<<<(HSEG + 3) / 4, 256, 0, stream>>>(offT, sortedAll, xl, ef16);
    k_no2<<<(NSEG + 3) / 4, 256, 0, stream>>>(offT, sortedAll, ef16, b_conv, mixin16);
    k_mix<<<512, 256, 0, stream>>>(mixin16, W_mix, b_mix, hbuf16);
    k_gru<<<512, 256, 0, stream>>>(hbuf16, h_prev, W_ih, W_hh, b_ih, b_hh,
                                   W_ro, b_ro, out_h, out_o);
}

// Round 9
// 552.667 us; speedup vs baseline: 1.0214x; 1.0214x over previous
//
#include <hip/hip_runtime.h>
#include <hip/hip_bf16.h>

#define N_NODES 100000
#define N_HEDGES 20000
#define N_EDGES 800000
#define HSEG (2 * N_HEDGES)            // 40000 hedge segments (t,h)
#define NSEG (2 * N_NODES)             // 200000 node segments (t,n)
#define MSEG (HSEG + NSEG)             // 240000 segments
#define NSUB 8                          // XCD-private sub-lists (blockIdx&7)
#define TOT (NSUB * MSEG)               // 1,920,000 counters
#define SCAN_BLOCKS ((TOT + 2047) / 2048)  // 938

typedef __hip_bfloat16 bf16;
typedef __attribute__((ext_vector_type(8))) short bf16x8;
typedef __attribute__((ext_vector_type(4))) float f32x4;

__device__ __forceinline__ float b2f(bf16 v) { return __bfloat162float(v); }
__device__ __forceinline__ bf16 f2b(float v) { return __float2bfloat16(v); }
__device__ __forceinline__ short f2s(float v) {
    bf16 b = __float2bfloat16(v);
    return *reinterpret_cast<short*>(&b);
}
__device__ __forceinline__ bf16x8 pack8(float4 a, float4 b) {
    bf16x8 r = {f2s(a.x), f2s(a.y), f2s(a.z), f2s(a.w),
                f2s(b.x), f2s(b.y), f2s(b.z), f2s(b.w)};
    return r;
}

// ---------------------------------------------------------------------------
// MFMA conv: xl[t] = x @ W_conv[t], one wave per 16-row tile, both types.
// ---------------------------------------------------------------------------
__global__ __launch_bounds__(256) void k_conv(const float* __restrict__ x,
                                              const float* __restrict__ Wc,
                                              bf16* __restrict__ xl) {
    __shared__ bf16 Wpk[2 * 2 * 4 * 64 * 8];  // 16 KB
    for (int i = threadIdx.x; i < 2 * 2 * 4 * 64 * 8; i += 256) {
        int j = i & 7;
        int ln = (i >> 3) & 63;
        int r2 = i >> 9;
        int ct = r2 & 3;
        int kt = (r2 >> 2) & 1;
        int t = r2 >> 3;
        int k = kt * 32 + ((ln >> 4) << 3) + j;
        int n = ct * 16 + (ln & 15);
        Wpk[i] = f2b(Wc[((size_t)t * 64 + k) * 64 + n]);
    }
    __syncthreads();
    int wid = threadIdx.x >> 6, lane = threadIdx.x & 63;
    int quad = lane >> 4, l16 = lane & 15;
    int wave = blockIdx.x * 4 + wid, n_waves = gridDim.x * 4;
    const f32x4 zero = {0.f, 0.f, 0.f, 0.f};
    for (int tile = wave; tile < N_NODES / 16; tile += n_waves) {
        int row0 = tile * 16;
        const float* xp = x + (size_t)(row0 + l16) * 64 + quad * 8;
        bf16x8 a0 = pack8(*(const float4*)xp, *(const float4*)(xp + 4));
        bf16x8 a1 = pack8(*(const float4*)(xp + 32), *(const float4*)(xp + 36));
#define LDBC(t, kt, ct) (*(const bf16x8*)&Wpk[((((t)*2 + (kt)) * 4 + (ct)) * 64 + lane) * 8])
#pragma unroll
        for (int t = 0; t < 2; ++t) {
#pragma unroll
            for (int ct = 0; ct < 4; ++ct) {
                f32x4 acc = __builtin_amdgcn_mfma_f32_16x16x32_bf16(a0, LDBC(t, 0, ct), zero, 0, 0, 0);
                acc = __builtin_amdgcn_mfma_f32_16x16x32_bf16(a1, LDBC(t, 1, ct), acc, 0, 0, 0);
#pragma unroll
                for (int rg = 0; rg < 4; ++rg) {
                    int row = row0 + quad * 4 + rg;
                    xl[(size_t)t * N_NODES * 64 + (size_t)row * 64 + ct * 16 + l16] = f2b(acc[rg]);
                }
            }
        }
#undef LDBC
    }
}

// ---------------------------------------------------------------------------
// Histogram into XCD-private counters cnt[sub][seg], sub = blockIdx&7.
// ---------------------------------------------------------------------------
__global__ __launch_bounds__(256) void k_hist(const int* __restrict__ node_idx,
                                              const int* __restrict__ hedge_idx,
                                              const int* __restrict__ attr,
                                              int* __restrict__ cnt) {
    int e = blockIdx.x * 256 + threadIdx.x;
    int base = (blockIdx.x & (NSUB - 1)) * MSEG;
    if (e < N_EDGES) {
        int t = attr[e];
        atomicAdd(&cnt[base + t * N_HEDGES + hedge_idx[e]], 1);
        atomicAdd(&cnt[base + HSEG + t * N_NODES + node_idx[e]], 1);
    }
}

// ---------------------------------------------------------------------------
// Scan 1/3: 2048 elems/block (256 thr x 8), partial exclusive scan + bsum.
// ---------------------------------------------------------------------------
__global__ __launch_bounds__(256) void k_scan1(const int* __restrict__ cnt,
                                               int* __restrict__ off,
                                               int* __restrict__ bsum) {
    __shared__ int s[256];
    int base = blockIdx.x * 2048 + threadIdx.x * 8;
    int v[8];
    int tsum = 0;
#pragma unroll
    for (int j = 0; j < 8; ++j) {
        int g = base + j;
        v[j] = (g < TOT) ? cnt[g] : 0;
        tsum += v[j];
    }
    s[threadIdx.x] = tsum;
    __syncthreads();
    for (int o = 1; o < 256; o <<= 1) {
        int t = (threadIdx.x >= o) ? s[threadIdx.x - o] : 0;
        __syncthreads();
        s[threadIdx.x] += t;
        __syncthreads();
    }
    int run = s[threadIdx.x] - tsum;
#pragma unroll
    for (int j = 0; j < 8; ++j) {
        int g = base + j;
        if (g < TOT) off[g] = run;
        run += v[j];
    }
    if (threadIdx.x == 255) bsum[blockIdx.x] = s[255];
}

// ---------------------------------------------------------------------------
// Scan 2/3: exclusive scan of SCAN_BLOCKS (<=1024) block sums, one block.
// ---------------------------------------------------------------------------
__global__ __launch_bounds__(1024) void k_scan2(int* __restrict__ bsum) {
    __shared__ int s[1024];
    int tid = threadIdx.x;
    int v = (tid < SCAN_BLOCKS) ? bsum[tid] : 0;
    s[tid] = v;
    __syncthreads();
    for (int o = 1; o < 1024; o <<= 1) {
        int t = (tid >= o) ? s[tid - o] : 0;
        __syncthreads();
        s[tid] += t;
        __syncthreads();
    }
    if (tid < SCAN_BLOCKS) bsum[tid] = s[tid] - v;
}

// ---------------------------------------------------------------------------
// Scan 3/3: final off + cursor copy + TRANSPOSED offsets offT[seg][8].
// Sentinel row offT[MSEG][k] = off[(k+1)*MSEG].
// ---------------------------------------------------------------------------
__global__ __launch_bounds__(256) void k_scan3(int* __restrict__ off,
                                               const int* __restrict__ bsum,
                                               int* __restrict__ cursor,
                                               int* __restrict__ offT) {
    int base = blockIdx.x * 2048 + threadIdx.x * 8;
    int add = bsum[blockIdx.x];
#pragma unroll
    for (int j = 0; j < 8; ++j) {
        int g = base + j;
        if (g < TOT) {
            int v = off[g] + add;
            off[g] = v;
            cursor[g] = v;
            int k = g / MSEG, s = g - k * MSEG;
            offT[s * NSUB + k] = v;
            if (s == 0 && k > 0) offT[MSEG * NSUB + (k - 1)] = v;  // end of sub k-1
        }
    }
    if (base == 0) offT[MSEG * NSUB + 7] = 2 * N_EDGES;
}

// ---------------------------------------------------------------------------
// Scatter into XCD-private sub-lists (sub = blockIdx&7).
// ---------------------------------------------------------------------------
__global__ __launch_bounds__(256) void k_scatter(const int* __restrict__ node_idx,
                                                 const int* __restrict__ hedge_idx,
                                                 const int* __restrict__ attr,
                                                 int* __restrict__ cursor,
                                                 int* __restrict__ sortedAll) {
    int e = blockIdx.x * 256 + threadIdx.x;
    int base = (blockIdx.x & (NSUB - 1)) * MSEG;
    if (e < N_EDGES) {
        int t = attr[e], n = node_idx[e], h = hedge_idx[e];
        int p1 = atomicAdd(&cursor[base + t * N_HEDGES + h], 1);
        sortedAll[p1] = t * N_NODES + n;
        int p2 = atomicAdd(&cursor[base + HSEG + t * N_NODES + n], 1);
        sortedAll[p2] = t * N_HEDGES + h;
    }
}

// ---------------------------------------------------------------------------
// Quad-row segment gather: each lane loads 8B (4 bf16), so 16 lanes cover a
// 128B row and ONE wave-load gathers 4 rows from 4 sub-lists (quarter q <->
// sub g*4+q). 4x fewer load issues / loop iters than wave-per-row (prev:
// 107us on node side, issue+latency bound). Clamped branch-free loads with
// mask-multiply; quarters combined via shfl_xor(16/32).
// acc[j] = sum over rows of feature 4*(lane&15)+j  (valid on lanes 0..15).
// ---------------------------------------------------------------------------
template <int ROW_MAX>
__device__ __forceinline__ void seg_gather4(const int* __restrict__ offT,
                                            const int* __restrict__ sortedAll,
                                            const bf16* __restrict__ rows,
                                            int s, int lane, float acc[4],
                                            int* total) {
    int l16 = lane & 15, q = lane >> 4;
    int4 b0 = *(const int4*)&offT[s * NSUB];
    int4 b1 = *(const int4*)&offT[s * NSUB + 4];
    int4 e0 = *(const int4*)&offT[(s + 1) * NSUB];
    int4 e1 = *(const int4*)&offT[(s + 1) * NSUB + 4];
    int beg[8] = {b0.x, b0.y, b0.z, b0.w, b1.x, b1.y, b1.z, b1.w};
    int cnt[8] = {e0.x - b0.x, e0.y - b0.y, e0.z - b0.z, e0.w - b0.w,
                  e1.x - b1.x, e1.y - b1.y, e1.z - b1.z, e1.w - b1.w};
    int tot = 0;
#pragma unroll
    for (int k = 0; k < 8; ++k) tot += cnt[k];
    *total = tot;
    acc[0] = acc[1] = acc[2] = acc[3] = 0.f;
#pragma unroll
    for (int g = 0; g < 2; ++g) {
        int c0 = cnt[g * 4], c1 = cnt[g * 4 + 1], c2 = cnt[g * 4 + 2], c3 = cnt[g * 4 + 3];
        int p0 = beg[g * 4], p1 = beg[g * 4 + 1], p2 = beg[g * 4 + 2], p3 = beg[g * 4 + 3];
        int cm = max(max(c0, c1), max(c2, c3));
        // per-lane selected count/base for this lane's quarter
        int cq = q < 2 ? (q == 0 ? c0 : c1) : (q == 2 ? c2 : c3);
        for (int r = 0; r < cm; ++r) {
            int i0 = sortedAll[min(p0 + r, 2 * N_EDGES - 1)];
            int i1 = sortedAll[min(p1 + r, 2 * N_EDGES - 1)];
            int i2 = sortedAll[min(p2 + r, 2 * N_EDGES - 1)];
            int i3 = sortedAll[min(p3 + r, 2 * N_EDGES - 1)];
            int idx = q < 2 ? (q == 0 ? i0 : i1) : (q == 2 ? i2 : i3);
            float m = (r < cq) ? 1.f : 0.f;
            int safe = min(max(idx, 0), ROW_MAX - 1);
            uint2 v = *(const uint2*)(rows + (size_t)safe * 64 + l16 * 4);
            acc[0] += m * __uint_as_float(v.x << 16);
            acc[1] += m * __uint_as_float(v.x & 0xffff0000u);
            acc[2] += m * __uint_as_float(v.y << 16);
            acc[3] += m * __uint_as_float(v.y & 0xffff0000u);
        }
    }
#pragma unroll
    for (int j = 0; j < 4; ++j) {
        acc[j] += __shfl_xor(acc[j], 16);
        acc[j] += __shfl_xor(acc[j], 32);
    }
}

// CSR node->hedge: ef[t][h] = (1/B) * sum xl rows.
__global__ __launch_bounds__(256) void k_ef2(const int* __restrict__ offT,
                                             const int* __restrict__ sortedAll,
                                             const bf16* __restrict__ xl,
                                             bf16* __restrict__ ef16) {
    int wid = threadIdx.x >> 6, lane = threadIdx.x & 63;
    int s = blockIdx.x * 4 + wid;
    if (s >= HSEG) return;
    float acc[4];
    int c;
    seg_gather4<2 * N_NODES>(offT, sortedAll, xl, s, lane, acc, &c);
    float scale = c > 0 ? 1.0f / (float)c : 0.f;
    if (lane < 16) {
        uint lo = (uint)(unsigned short)f2s(acc[0] * scale) |
                  ((uint)(unsigned short)f2s(acc[1] * scale) << 16);
        uint hi = (uint)(unsigned short)f2s(acc[2] * scale) |
                  ((uint)(unsigned short)f2s(acc[3] * scale) << 16);
        *(uint2*)(ef16 + (size_t)s * 64 + lane * 4) = make_uint2(lo, hi);
    }
}

// CSR hedge->node: mixin[t][n] = (1/D) * sum ef rows + b_conv[t].
__global__ __launch_bounds__(256) void k_no2(const int* __restrict__ offT,
                                             const int* __restrict__ sortedAll,
                                             const bf16* __restrict__ ef16,
                                             const float* __restrict__ bconv,
                                             bf16* __restrict__ mixin16) {
    int wid = threadIdx.x >> 6, lane = threadIdx.x & 63;
    int j = blockIdx.x * 4 + wid;
    if (j >= NSEG) return;
    float acc[4];
    int c;
    seg_gather4<HSEG>(offT, sortedAll, ef16, HSEG + j, lane, acc, &c);
    float scale = c > 0 ? 1.0f / (float)c : 0.f;
    if (lane < 16) {
        int t = j / N_NODES;
        float4 bc = *(const float4*)&bconv[t * 64 + lane * 4];
        uint lo = (uint)(unsigned short)f2s(acc[0] * scale + bc.x) |
                  ((uint)(unsigned short)f2s(acc[1] * scale + bc.y) << 16);
        uint hi = (uint)(unsigned short)f2s(acc[2] * scale + bc.z) |
                  ((uint)(unsigned short)f2s(acc[3] * scale + bc.w) << 16);
        *(uint2*)(mixin16 + (size_t)j * 64 + lane * 4) = make_uint2(lo, hi);
    }
}

// ---------------------------------------------------------------------------
// MFMA mix: h = relu(mixin @ W_mix + b_mix), bf16 out. K=128 (4 k-frags).
// ---------------------------------------------------------------------------
__global__ __launch_bounds__(256) void k_mix(const bf16* __restrict__ mixin16,
                                             const float* __restrict__ Wm_g,
                                             const float* __restrict__ bm_g,
                                             bf16* __restrict__ hbuf16) {
    __shared__ bf16 Wpk[4 * 4 * 64 * 8];  // 16 KB
    for (int i = threadIdx.x; i < 4 * 4 * 64 * 8; i += 256) {
        int j = i & 7;
        int ln = (i >> 3) & 63;
        int r2 = i >> 9;
        int ct = r2 & 3;
        int kt = r2 >> 2;
        int k = kt * 32 + ((ln >> 4) << 3) + j;
        int n = ct * 16 + (ln & 15);
        Wpk[i] = f2b(Wm_g[(size_t)k * 64 + n]);
    }
    __syncthreads();
    int wid = threadIdx.x >> 6, lane = threadIdx.x & 63;
    int quad = lane >> 4, l16 = lane & 15;
    float bmv[4];
#pragma unroll
    for (int ct = 0; ct < 4; ++ct) bmv[ct] = bm_g[ct * 16 + l16];

    int wave = blockIdx.x * 4 + wid, n_waves = gridDim.x * 4;
    for (int tile = wave; tile < N_NODES / 16; tile += n_waves) {
        int row0 = tile * 16;
        int arow = row0 + l16;
        bf16x8 af[4];
#pragma unroll
        for (int kt = 0; kt < 4; ++kt) {
            const bf16* src = (kt < 2)
                ? mixin16 + (size_t)arow * 64 + kt * 32 + quad * 8
                : mixin16 + ((size_t)N_NODES + arow) * 64 + (kt - 2) * 32 + quad * 8;
            af[kt] = *(const bf16x8*)src;
        }
#define LDBM(kt, ct) (*(const bf16x8*)&Wpk[(((kt)*4 + (ct)) * 64 + lane) * 8])
#pragma unroll
        for (int ct = 0; ct < 4; ++ct) {
            f32x4 acc = {bmv[ct], bmv[ct], bmv[ct], bmv[ct]};
#pragma unroll
            for (int kt = 0; kt < 4; ++kt)
                acc = __builtin_amdgcn_mfma_f32_16x16x32_bf16(af[kt], LDBM(kt, ct), acc, 0, 0, 0);
#pragma unroll
            for (int rg = 0; rg < 4; ++rg) {
                int row = row0 + quad * 4 + rg;
                hbuf16[(size_t)row * 64 + ct * 16 + l16] = f2b(fmaxf(acc[rg], 0.f));
            }
        }
#undef LDBM
    }
}

// ---------------------------------------------------------------------------
// MFMA GRU: one wave per 16-row tile; h_prev cast fp32->bf16 inline.
// ---------------------------------------------------------------------------
#define GRU_TILES (N_NODES / 16)
__global__ __launch_bounds__(256) void k_gru(const bf16* __restrict__ hbuf16,
                                             const float* __restrict__ h_prev,
                                             const float* __restrict__ Wih_g,
                                             const float* __restrict__ Whh_g,
                                             const float* __restrict__ bih_g,
                                             const float* __restrict__ bhh_g,
                                             const float* __restrict__ Wro_g,
                                             const float* __restrict__ bro_g,
                                             float* __restrict__ out_h,
                                             float* __restrict__ out_o) {
    __shared__ bf16 Wpk[2 * 2 * 12 * 64 * 8];  // 48 KB
    for (int i = threadIdx.x; i < 2 * 2 * 12 * 64 * 8; i += 256) {
        int j = i & 7;
        int r = i >> 3;
        int ln = r & 63;
        int r2 = r >> 6;
        int ct = r2 % 12;
        int r3 = r2 / 12;
        int kt = r3 & 1;
        int mat = r3 >> 1;
        int k = kt * 32 + ((ln >> 4) << 3) + j;
        int n = ct * 16 + (ln & 15);
        float v = mat == 0 ? Wih_g[k * 192 + n] : Whh_g[k * 192 + n];
        Wpk[i] = f2b(v);
    }
    __syncthreads();

    int wid = threadIdx.x >> 6, lane = threadIdx.x & 63;
    int quad = lane >> 4, l16 = lane & 15;

    float bi[3][4], bh[3][4], wv[4][3];
    for (int g = 0; g < 3; ++g)
        for (int cc = 0; cc < 4; ++cc) {
            bi[g][cc] = bih_g[g * 64 + cc * 16 + l16];
            bh[g][cc] = bhh_g[g * 64 + cc * 16 + l16];
        }
    for (int cc = 0; cc < 4; ++cc)
        for (int c = 0; c < 3; ++c)
            wv[cc][c] = Wro_g[(cc * 16 + l16) * 64 + c];
    float bro0 = bro_g[0], bro1 = bro_g[1], bro2 = bro_g[2];

    int wave = blockIdx.x * 4 + wid;
    int n_waves = gridDim.x * 4;
    const f32x4 zero = {0.f, 0.f, 0.f, 0.f};

    for (int tile = wave; tile < GRU_TILES; tile += n_waves) {
        int row0 = tile * 16;
        const bf16* ha_p = hbuf16 + (size_t)(row0 + l16) * 64 + quad * 8;
        bf16x8 ha0 = *(const bf16x8*)ha_p;
        bf16x8 ha1 = *(const bf16x8*)(ha_p + 32);
        const float* pp = h_prev + (size_t)(row0 + l16) * 64 + quad * 8;
        bf16x8 pa0 = pack8(*(const float4*)pp, *(const float4*)(pp + 4));
        bf16x8 pa1 = pack8(*(const float4*)(pp + 32), *(const float4*)(pp + 36));

        float p[4][3];
#pragma unroll
        for (int rg = 0; rg < 4; ++rg) p[rg][0] = p[rg][1] = p[rg][2] = 0.f;

#pragma unroll
        for (int cc = 0; cc < 4; ++cc) {
#define LDB(mat, kt, ct) (*(const bf16x8*)&Wpk[((((mat)*2 + (kt)) * 12 + (ct)) * 64 + lane) * 8])
            f32x4 gir = __builtin_amdgcn_mfma_f32_16x16x32_bf16(ha0, LDB(0, 0, cc), zero, 0, 0, 0);
            gir = __builtin_amdgcn_mfma_f32_16x16x32_bf16(ha1, LDB(0, 1, cc), gir, 0, 0, 0);
            f32x4 giz = __builtin_amdgcn_mfma_f32_16x16x32_bf16(ha0, LDB(0, 0, cc + 4), zero, 0, 0, 0);
            giz = __builtin_amdgcn_mfma_f32_16x16x32_bf16(ha1, LDB(0, 1, cc + 4), giz, 0, 0, 0);
            f32x4 gin = __builtin_amdgcn_mfma_f32_16x16x32_bf16(ha0, LDB(0, 0, cc + 8), zero, 0, 0, 0);
            gin = __builtin_amdgcn_mfma_f32_16x16x32_bf16(ha1, LDB(0, 1, cc + 8), gin, 0, 0, 0);
            f32x4 ghr = __builtin_amdgcn_mfma_f32_16x16x32_bf16(pa0, LDB(1, 0, cc), zero, 0, 0, 0);
            ghr = __builtin_amdgcn_mfma_f32_16x16x32_bf16(pa1, LDB(1, 1, cc), ghr, 0, 0, 0);
            f32x4 ghz = __builtin_amdgcn_mfma_f32_16x16x32_bf16(pa0, LDB(1, 0, cc + 4), zero, 0, 0, 0);
            ghz = __builtin_amdgcn_mfma_f32_16x16x32_bf16(pa1, LDB(1, 1, cc + 4), ghz, 0, 0, 0);
            f32x4 ghn = __builtin_amdgcn_mfma_f32_16x16x32_bf16(pa0, LDB(1, 0, cc + 8), zero, 0, 0, 0);
            ghn = __builtin_amdgcn_mfma_f32_16x16x32_bf16(pa1, LDB(1, 1, cc + 8), ghn, 0, 0, 0);
#undef LDB
#pragma unroll
            for (int rg = 0; rg < 4; ++rg) {
                int row = row0 + quad * 4 + rg;
                float pv = h_prev[(size_t)row * 64 + cc * 16 + l16];
                float rr = 1.f / (1.f + __expf(-(gir[rg] + bi[0][cc] + ghr[rg] + bh[0][cc])));
                float zz = 1.f / (1.f + __expf(-(giz[rg] + bi[1][cc] + ghz[rg] + bh[1][cc])));
                float nn = tanhf(gin[rg] + bi[2][cc] + rr * (ghn[rg] + bh[2][cc]));
                float hn = (1.f - zz) * nn + zz * pv;
                out_h[(size_t)row * 64 + cc * 16 + l16] = hn;
                p[rg][0] += hn * wv[cc][0];
                p[rg][1] += hn * wv[cc][1];
                p[rg][2] += hn * wv[cc][2];
            }
        }
#pragma unroll
        for (int rg = 0; rg < 4; ++rg) {
#pragma unroll
            for (int m = 1; m < 16; m <<= 1) {
                p[rg][0] += __shfl_xor(p[rg][0], m);
                p[rg][1] += __shfl_xor(p[rg][1], m);
                p[rg][2] += __shfl_xor(p[rg][2], m);
            }
        }
        if (l16 == 0) {
#pragma unroll
            for (int rg = 0; rg < 4; ++rg) {
                int row = row0 + quad * 4 + rg;
                out_o[(size_t)row * 3 + 0] = p[rg][0] + bro0;
                out_o[(size_t)row * 3 + 1] = p[rg][1] + bro1;
                out_o[(size_t)row * 3 + 2] = p[rg][2] + bro2;
            }
        }
    }
}

extern "C" void kernel_launch(void* const* d_in, const int* in_sizes, int n_in,
                              void* d_out, int out_size, void* d_ws, size_t ws_size,
                              hipStream_t stream) {
    const float* x        = (const float*)d_in[0];
    const float* h_prev   = (const float*)d_in[1];
    const int* node_idx   = (const int*)d_in[2];
    const int* hedge_idx  = (const int*)d_in[3];
    const int* edge_attr  = (const int*)d_in[4];
    const float* W_conv   = (const float*)d_in[5];
    const float* b_conv   = (const float*)d_in[6];
    const float* W_mix    = (const float*)d_in[7];
    const float* b_mix    = (const float*)d_in[8];
    const float* W_ih     = (const float*)d_in[9];
    const float* W_hh     = (const float*)d_in[10];
    const float* b_ih     = (const float*)d_in[11];
    const float* b_hh     = (const float*)d_in[12];
    const float* W_ro     = (const float*)d_in[13];
    const float* b_ro     = (const float*)d_in[14];

    char* p = (char*)d_ws;
    auto alloc = [&](size_t bytes) {
        char* r = p;
        p += (bytes + 63) & ~(size_t)63;
        return r;
    };
    int* cnt       = (int*)alloc((size_t)TOT * 4);        // [zeroed]
    int* off       = (int*)alloc((size_t)(TOT + 1) * 4);
    int* cursor    = (int*)alloc((size_t)TOT * 4);
    int* offT      = (int*)alloc((size_t)(MSEG + 1) * NSUB * 4);
    int* bsum      = (int*)alloc(1024 * 4);
    int* sortedAll = (int*)alloc((size_t)2 * N_EDGES * 4);
    bf16* xl       = (bf16*)alloc((size_t)2 * N_NODES * 64 * 2);
    bf16* ef16     = (bf16*)alloc((size_t)HSEG * 64 * 2);
    bf16* hbuf16   = (bf16*)alloc((size_t)N_NODES * 64 * 2);
    bf16* mixin16  = xl;  // alias: xl dead after k_ef2

    hipMemsetAsync(cnt, 0, (size_t)TOT * 4, stream);

    float* out_h = (float*)d_out;
    float* out_o = out_h + (size_t)N_NODES * 64;

    k_conv<<<512, 256, 0, stream>>>(x, W_conv, xl);
    k_hist<<<(N_EDGES + 255) / 256, 256, 0, stream>>>(node_idx, hedge_idx, edge_attr, cnt);
    k_scan1<<<SCAN_BLOCKS, 256, 0, stream>>>(cnt, off, bsum);
    k_scan2<<<1, 1024, 0, stream>>>(bsum);
    k_scan3<<<SCAN_BLOCKS, 256, 0, stream>>>(off, bsum, cursor, offT);
    k_scatter<<<(N_EDGES + 255) / 256, 256, 0, stream>>>(node_idx, hedge_idx, edge_attr,
                                                         cursor, sortedAll);
    k_ef2<<<(HSEG + 3) / 4, 256, 0, stream>>>(offT, sortedAll, xl, ef16);
    k_no2<<<(NSEG + 3) / 4, 256, 0, stream>>>(offT, sortedAll, ef16, b_conv, mixin16);
    k_mix<<<512, 256, 0, stream>>>(mixin16, W_mix, b_mix, hbuf16);
    k_gru<<<512, 256, 0, stream>>>(hbuf16, h_prev, W_ih, W_hh, b_ih, b_hh,
                                   W_ro, b_ro, out_h, out_o);
}

// Round 10
// 485.748 us; speedup vs baseline: 1.1622x; 1.1378x over previous
//
#include <hip/hip_runtime.h>
#include <hip/hip_bf16.h>

#define N_NODES 100000
#define N_HEDGES 20000
#define N_EDGES 800000
#define HSEG (2 * N_HEDGES)            // 40000 hedge segments (t,h)
#define NSEG (2 * N_NODES)             // 200000 node segments (t,n)
#define MSEG (HSEG + NSEG)             // 240000 segments
#define NSUB 8                          // XCD-private sub-lists (blockIdx&7)
#define TOT (NSUB * MSEG)               // 1,920,000 counters
#define SCAN_BLOCKS ((TOT + 2047) / 2048)  // 938

typedef __hip_bfloat16 bf16;
typedef __attribute__((ext_vector_type(8))) short bf16x8;
typedef __attribute__((ext_vector_type(4))) float f32x4;

__device__ __forceinline__ float b2f(bf16 v) { return __bfloat162float(v); }
__device__ __forceinline__ bf16 f2b(float v) { return __float2bfloat16(v); }
__device__ __forceinline__ short f2s(float v) {
    bf16 b = __float2bfloat16(v);
    return *reinterpret_cast<short*>(&b);
}
__device__ __forceinline__ bf16x8 pack8(float4 a, float4 b) {
    bf16x8 r = {f2s(a.x), f2s(a.y), f2s(a.z), f2s(a.w),
                f2s(b.x), f2s(b.y), f2s(b.z), f2s(b.w)};
    return r;
}

// ---------------------------------------------------------------------------
// MFMA conv: xl[t] = x @ W_conv[t], one wave per 16-row tile, both types.
// ---------------------------------------------------------------------------
__global__ __launch_bounds__(256) void k_conv(const float* __restrict__ x,
                                              const float* __restrict__ Wc,
                                              bf16* __restrict__ xl) {
    __shared__ bf16 Wpk[2 * 2 * 4 * 64 * 8];  // 16 KB
    for (int i = threadIdx.x; i < 2 * 2 * 4 * 64 * 8; i += 256) {
        int j = i & 7;
        int ln = (i >> 3) & 63;
        int r2 = i >> 9;
        int ct = r2 & 3;
        int kt = (r2 >> 2) & 1;
        int t = r2 >> 3;
        int k = kt * 32 + ((ln >> 4) << 3) + j;
        int n = ct * 16 + (ln & 15);
        Wpk[i] = f2b(Wc[((size_t)t * 64 + k) * 64 + n]);
    }
    __syncthreads();
    int wid = threadIdx.x >> 6, lane = threadIdx.x & 63;
    int quad = lane >> 4, l16 = lane & 15;
    int wave = blockIdx.x * 4 + wid, n_waves = gridDim.x * 4;
    const f32x4 zero = {0.f, 0.f, 0.f, 0.f};
    for (int tile = wave; tile < N_NODES / 16; tile += n_waves) {
        int row0 = tile * 16;
        const float* xp = x + (size_t)(row0 + l16) * 64 + quad * 8;
        bf16x8 a0 = pack8(*(const float4*)xp, *(const float4*)(xp + 4));
        bf16x8 a1 = pack8(*(const float4*)(xp + 32), *(const float4*)(xp + 36));
#define LDBC(t, kt, ct) (*(const bf16x8*)&Wpk[((((t)*2 + (kt)) * 4 + (ct)) * 64 + lane) * 8])
#pragma unroll
        for (int t = 0; t < 2; ++t) {
#pragma unroll
            for (int ct = 0; ct < 4; ++ct) {
                f32x4 acc = __builtin_amdgcn_mfma_f32_16x16x32_bf16(a0, LDBC(t, 0, ct), zero, 0, 0, 0);
                acc = __builtin_amdgcn_mfma_f32_16x16x32_bf16(a1, LDBC(t, 1, ct), acc, 0, 0, 0);
#pragma unroll
                for (int rg = 0; rg < 4; ++rg) {
                    int row = row0 + quad * 4 + rg;
                    xl[(size_t)t * N_NODES * 64 + (size_t)row * 64 + ct * 16 + l16] = f2b(acc[rg]);
                }
            }
        }
#undef LDBC
    }
}

// ---------------------------------------------------------------------------
// Histogram into XCD-private counters cnt[sub][seg], sub = blockIdx&7.
// ---------------------------------------------------------------------------
__global__ __launch_bounds__(256) void k_hist(const int* __restrict__ node_idx,
                                              const int* __restrict__ hedge_idx,
                                              const int* __restrict__ attr,
                                              int* __restrict__ cnt) {
    int e = blockIdx.x * 256 + threadIdx.x;
    int base = (blockIdx.x & (NSUB - 1)) * MSEG;
    if (e < N_EDGES) {
        int t = attr[e];
        atomicAdd(&cnt[base + t * N_HEDGES + hedge_idx[e]], 1);
        atomicAdd(&cnt[base + HSEG + t * N_NODES + node_idx[e]], 1);
    }
}

// ---------------------------------------------------------------------------
// Scan 1/3: 2048 elems/block (256 thr x 8), partial exclusive scan + bsum.
// ---------------------------------------------------------------------------
__global__ __launch_bounds__(256) void k_scan1(const int* __restrict__ cnt,
                                               int* __restrict__ off,
                                               int* __restrict__ bsum) {
    __shared__ int s[256];
    int base = blockIdx.x * 2048 + threadIdx.x * 8;
    int v[8];
    int tsum = 0;
#pragma unroll
    for (int j = 0; j < 8; ++j) {
        int g = base + j;
        v[j] = (g < TOT) ? cnt[g] : 0;
        tsum += v[j];
    }
    s[threadIdx.x] = tsum;
    __syncthreads();
    for (int o = 1; o < 256; o <<= 1) {
        int t = (threadIdx.x >= o) ? s[threadIdx.x - o] : 0;
        __syncthreads();
        s[threadIdx.x] += t;
        __syncthreads();
    }
    int run = s[threadIdx.x] - tsum;
#pragma unroll
    for (int j = 0; j < 8; ++j) {
        int g = base + j;
        if (g < TOT) off[g] = run;
        run += v[j];
    }
    if (threadIdx.x == 255) bsum[blockIdx.x] = s[255];
}

// ---------------------------------------------------------------------------
// Scan 2/3: exclusive scan of SCAN_BLOCKS (<=1024) block sums, one block.
// ---------------------------------------------------------------------------
__global__ __launch_bounds__(1024) void k_scan2(int* __restrict__ bsum) {
    __shared__ int s[1024];
    int tid = threadIdx.x;
    int v = (tid < SCAN_BLOCKS) ? bsum[tid] : 0;
    s[tid] = v;
    __syncthreads();
    for (int o = 1; o < 1024; o <<= 1) {
        int t = (tid >= o) ? s[tid - o] : 0;
        __syncthreads();
        s[tid] += t;
        __syncthreads();
    }
    if (tid < SCAN_BLOCKS) bsum[tid] = s[tid] - v;
}

// ---------------------------------------------------------------------------
// Scan 3/3: final off + cursor copy + TRANSPOSED offsets offT[seg][8].
// Sentinel row offT[MSEG][k] = off[(k+1)*MSEG].
// ---------------------------------------------------------------------------
__global__ __launch_bounds__(256) void k_scan3(int* __restrict__ off,
                                               const int* __restrict__ bsum,
                                               int* __restrict__ cursor,
                                               int* __restrict__ offT) {
    int base = blockIdx.x * 2048 + threadIdx.x * 8;
    int add = bsum[blockIdx.x];
#pragma unroll
    for (int j = 0; j < 8; ++j) {
        int g = base + j;
        if (g < TOT) {
            int v = off[g] + add;
            off[g] = v;
            cursor[g] = v;
            int k = g / MSEG, s = g - k * MSEG;
            offT[s * NSUB + k] = v;
            if (s == 0 && k > 0) offT[MSEG * NSUB + (k - 1)] = v;  // end of sub k-1
        }
    }
    if (base == 0) offT[MSEG * NSUB + 7] = 2 * N_EDGES;
}

// ---------------------------------------------------------------------------
// Scatter into XCD-private sub-lists (sub = blockIdx&7).
// ---------------------------------------------------------------------------
__global__ __launch_bounds__(256) void k_scatter(const int* __restrict__ node_idx,
                                                 const int* __restrict__ hedge_idx,
                                                 const int* __restrict__ attr,
                                                 int* __restrict__ cursor,
                                                 int* __restrict__ sortedAll) {
    int e = blockIdx.x * 256 + threadIdx.x;
    int base = (blockIdx.x & (NSUB - 1)) * MSEG;
    if (e < N_EDGES) {
        int t = attr[e], n = node_idx[e], h = hedge_idx[e];
        int p1 = atomicAdd(&cursor[base + t * N_HEDGES + h], 1);
        sortedAll[p1] = t * N_NODES + n;
        int p2 = atomicAdd(&cursor[base + HSEG + t * N_NODES + n], 1);
        sortedAll[p2] = t * N_HEDGES + h;
    }
}

// ---------------------------------------------------------------------------
// Quarter-per-segment gather: each 16-lane quarter owns one segment (4 per
// wave). One coalesced load ov = offT[seg0*8 + lane] provides all 4 quarters'
// 8 begs + 8 ends (offT rows contiguous: ends of s == begs of s+1). Uniform
// k-loop with per-quarter exact bounds via shfl — no clamped/masked loads
// (round-9's mask-multiply doubled VALU and went flat). 16 lanes x 8B = one
// 128B row per quarter per iter; 4 independent gathers in flight per wave.
// Epilogue: lane owns feats 4*l16..+3 of its quarter's segment — all 64
// lanes write one coalesced 512B store, NO cross-lane reduction.
// ---------------------------------------------------------------------------
__device__ __forceinline__ void seg_quarter(const int* __restrict__ offT,
                                            const int* __restrict__ sortedAll,
                                            const bf16* __restrict__ rows,
                                            int seg0, int lane,
                                            float acc[4], int* total) {
    int q = lane >> 4, l16 = lane & 15;
    int ov = offT[(size_t)seg0 * NSUB + lane];  // begs+ends for 4 quarters
    acc[0] = acc[1] = acc[2] = acc[3] = 0.f;
    int tot = 0;
#pragma unroll
    for (int k = 0; k < NSUB; ++k) {
        int myb = __shfl(ov, q * NSUB + k);
        int mye = __shfl(ov, q * NSUB + k + NSUB);
        tot += mye - myb;
        for (int i = myb; i < mye; ++i) {
            int idx = sortedAll[i];  // 16 lanes same addr (broadcast)
            uint2 v = *(const uint2*)(rows + (size_t)idx * 64 + l16 * 4);
            acc[0] += __uint_as_float(v.x << 16);
            acc[1] += __uint_as_float(v.x & 0xffff0000u);
            acc[2] += __uint_as_float(v.y << 16);
            acc[3] += __uint_as_float(v.y & 0xffff0000u);
        }
    }
    *total = tot;
}

// CSR node->hedge: ef[t][h] = (1/B) * sum xl rows. 16 segments per block.
__global__ __launch_bounds__(256) void k_ef2(const int* __restrict__ offT,
                                             const int* __restrict__ sortedAll,
                                             const bf16* __restrict__ xl,
                                             bf16* __restrict__ ef16) {
    int wid = threadIdx.x >> 6, lane = threadIdx.x & 63;
    int seg0 = (blockIdx.x * 4 + wid) * 4;
    if (seg0 >= HSEG) return;
    float acc[4];
    int tot;
    seg_quarter(offT, sortedAll, xl, seg0, lane, acc, &tot);
    float scale = tot > 0 ? 1.0f / (float)tot : 0.f;
    int s = seg0 + (lane >> 4), l16 = lane & 15;
    uint lo = (uint)(unsigned short)f2s(acc[0] * scale) |
              ((uint)(unsigned short)f2s(acc[1] * scale) << 16);
    uint hi = (uint)(unsigned short)f2s(acc[2] * scale) |
              ((uint)(unsigned short)f2s(acc[3] * scale) << 16);
    *(uint2*)(ef16 + (size_t)s * 64 + l16 * 4) = make_uint2(lo, hi);
}

// CSR hedge->node: mixin[t][n] = (1/D) * sum ef rows + b_conv[t].
__global__ __launch_bounds__(256) void k_no2(const int* __restrict__ offT,
                                             const int* __restrict__ sortedAll,
                                             const bf16* __restrict__ ef16,
                                             const float* __restrict__ bconv,
                                             bf16* __restrict__ mixin16) {
    int wid = threadIdx.x >> 6, lane = threadIdx.x & 63;
    int j0 = (blockIdx.x * 4 + wid) * 4;
    if (j0 >= NSEG) return;
    float acc[4];
    int tot;
    seg_quarter(offT, sortedAll, ef16, HSEG + j0, lane, acc, &tot);
    float scale = tot > 0 ? 1.0f / (float)tot : 0.f;
    int q = lane >> 4, l16 = lane & 15;
    int j = j0 + q;
    int t = (j >= N_NODES) ? 1 : 0;
    float4 bc = *(const float4*)&bconv[t * 64 + l16 * 4];
    uint lo = (uint)(unsigned short)f2s(acc[0] * scale + bc.x) |
              ((uint)(unsigned short)f2s(acc[1] * scale + bc.y) << 16);
    uint hi = (uint)(unsigned short)f2s(acc[2] * scale + bc.z) |
              ((uint)(unsigned short)f2s(acc[3] * scale + bc.w) << 16);
    *(uint2*)(mixin16 + (size_t)j * 64 + l16 * 4) = make_uint2(lo, hi);
}

// ---------------------------------------------------------------------------
// MFMA mix: h = relu(mixin @ W_mix + b_mix), bf16 out. K=128 (4 k-frags).
// ---------------------------------------------------------------------------
__global__ __launch_bounds__(256) void k_mix(const bf16* __restrict__ mixin16,
                                             const float* __restrict__ Wm_g,
                                             const float* __restrict__ bm_g,
                                             bf16* __restrict__ hbuf16) {
    __shared__ bf16 Wpk[4 * 4 * 64 * 8];  // 16 KB
    for (int i = threadIdx.x; i < 4 * 4 * 64 * 8; i += 256) {
        int j = i & 7;
        int ln = (i >> 3) & 63;
        int r2 = i >> 9;
        int ct = r2 & 3;
        int kt = r2 >> 2;
        int k = kt * 32 + ((ln >> 4) << 3) + j;
        int n = ct * 16 + (ln & 15);
        Wpk[i] = f2b(Wm_g[(size_t)k * 64 + n]);
    }
    __syncthreads();
    int wid = threadIdx.x >> 6, lane = threadIdx.x & 63;
    int quad = lane >> 4, l16 = lane & 15;
    float bmv[4];
#pragma unroll
    for (int ct = 0; ct < 4; ++ct) bmv[ct] = bm_g[ct * 16 + l16];

    int wave = blockIdx.x * 4 + wid, n_waves = gridDim.x * 4;
    for (int tile = wave; tile < N_NODES / 16; tile += n_waves) {
        int row0 = tile * 16;
        int arow = row0 + l16;
        bf16x8 af[4];
#pragma unroll
        for (int kt = 0; kt < 4; ++kt) {
            const bf16* src = (kt < 2)
                ? mixin16 + (size_t)arow * 64 + kt * 32 + quad * 8
                : mixin16 + ((size_t)N_NODES + arow) * 64 + (kt - 2) * 32 + quad * 8;
            af[kt] = *(const bf16x8*)src;
        }
#define LDBM(kt, ct) (*(const bf16x8*)&Wpk[(((kt)*4 + (ct)) * 64 + lane) * 8])
#pragma unroll
        for (int ct = 0; ct < 4; ++ct) {
            f32x4 acc = {bmv[ct], bmv[ct], bmv[ct], bmv[ct]};
#pragma unroll
            for (int kt = 0; kt < 4; ++kt)
                acc = __builtin_amdgcn_mfma_f32_16x16x32_bf16(af[kt], LDBM(kt, ct), acc, 0, 0, 0);
#pragma unroll
            for (int rg = 0; rg < 4; ++rg) {
                int row = row0 + quad * 4 + rg;
                hbuf16[(size_t)row * 64 + ct * 16 + l16] = f2b(fmaxf(acc[rg], 0.f));
            }
        }
#undef LDBM
    }
}

// ---------------------------------------------------------------------------
// MFMA GRU: one wave per 16-row tile; h_prev cast fp32->bf16 inline.
// ---------------------------------------------------------------------------
#define GRU_TILES (N_NODES / 16)
__global__ __launch_bounds__(256) void k_gru(const bf16* __restrict__ hbuf16,
                                             const float* __restrict__ h_prev,
                                             const float* __restrict__ Wih_g,
                                             const float* __restrict__ Whh_g,
                                             const float* __restrict__ bih_g,
                                             const float* __restrict__ bhh_g,
                                             const float* __restrict__ Wro_g,
                                             const float* __restrict__ bro_g,
                                             float* __restrict__ out_h,
                                             float* __restrict__ out_o) {
    __shared__ bf16 Wpk[2 * 2 * 12 * 64 * 8];  // 48 KB
    for (int i = threadIdx.x; i < 2 * 2 * 12 * 64 * 8; i += 256) {
        int j = i & 7;
        int r = i >> 3;
        int ln = r & 63;
        int r2 = r >> 6;
        int ct = r2 % 12;
        int r3 = r2 / 12;
        int kt = r3 & 1;
        int mat = r3 >> 1;
        int k = kt * 32 + ((ln >> 4) << 3) + j;
        int n = ct * 16 + (ln & 15);
        float v = mat == 0 ? Wih_g[k * 192 + n] : Whh_g[k * 192 + n];
        Wpk[i] = f2b(v);
    }
    __syncthreads();

    int wid = threadIdx.x >> 6, lane = threadIdx.x & 63;
    int quad = lane >> 4, l16 = lane & 15;

    float bi[3][4], bh[3][4], wv[4][3];
    for (int g = 0; g < 3; ++g)
        for (int cc = 0; cc < 4; ++cc) {
            bi[g][cc] = bih_g[g * 64 + cc * 16 + l16];
            bh[g][cc] = bhh_g[g * 64 + cc * 16 + l16];
        }
    for (int cc = 0; cc < 4; ++cc)
        for (int c = 0; c < 3; ++c)
            wv[cc][c] = Wro_g[(cc * 16 + l16) * 64 + c];
    float bro0 = bro_g[0], bro1 = bro_g[1], bro2 = bro_g[2];

    int wave = blockIdx.x * 4 + wid;
    int n_waves = gridDim.x * 4;
    const f32x4 zero = {0.f, 0.f, 0.f, 0.f};

    for (int tile = wave; tile < GRU_TILES; tile += n_waves) {
        int row0 = tile * 16;
        const bf16* ha_p = hbuf16 + (size_t)(row0 + l16) * 64 + quad * 8;
        bf16x8 ha0 = *(const bf16x8*)ha_p;
        bf16x8 ha1 = *(const bf16x8*)(ha_p + 32);
        const float* pp = h_prev + (size_t)(row0 + l16) * 64 + quad * 8;
        bf16x8 pa0 = pack8(*(const float4*)pp, *(const float4*)(pp + 4));
        bf16x8 pa1 = pack8(*(const float4*)(pp + 32), *(const float4*)(pp + 36));

        float p[4][3];
#pragma unroll
        for (int rg = 0; rg < 4; ++rg) p[rg][0] = p[rg][1] = p[rg][2] = 0.f;

#pragma unroll
        for (int cc = 0; cc < 4; ++cc) {
#define LDB(mat, kt, ct) (*(const bf16x8*)&Wpk[((((mat)*2 + (kt)) * 12 + (ct)) * 64 + lane) * 8])
            f32x4 gir = __builtin_amdgcn_mfma_f32_16x16x32_bf16(ha0, LDB(0, 0, cc), zero, 0, 0, 0);
            gir = __builtin_amdgcn_mfma_f32_16x16x32_bf16(ha1, LDB(0, 1, cc), gir, 0, 0, 0);
            f32x4 giz = __builtin_amdgcn_mfma_f32_16x16x32_bf16(ha0, LDB(0, 0, cc + 4), zero, 0, 0, 0);
            giz = __builtin_amdgcn_mfma_f32_16x16x32_bf16(ha1, LDB(0, 1, cc + 4), giz, 0, 0, 0);
            f32x4 gin = __builtin_amdgcn_mfma_f32_16x16x32_bf16(ha0, LDB(0, 0, cc + 8), zero, 0, 0, 0);
            gin = __builtin_amdgcn_mfma_f32_16x16x32_bf16(ha1, LDB(0, 1, cc + 8), gin, 0, 0, 0);
            f32x4 ghr = __builtin_amdgcn_mfma_f32_16x16x32_bf16(pa0, LDB(1, 0, cc), zero, 0, 0, 0);
            ghr = __builtin_amdgcn_mfma_f32_16x16x32_bf16(pa1, LDB(1, 1, cc), ghr, 0, 0, 0);
            f32x4 ghz = __builtin_amdgcn_mfma_f32_16x16x32_bf16(pa0, LDB(1, 0, cc + 4), zero, 0, 0, 0);
            ghz = __builtin_amdgcn_mfma_f32_16x16x32_bf16(pa1, LDB(1, 1, cc + 4), ghz, 0, 0, 0);
            f32x4 ghn = __builtin_amdgcn_mfma_f32_16x16x32_bf16(pa0, LDB(1, 0, cc + 8), zero, 0, 0, 0);
            ghn = __builtin_amdgcn_mfma_f32_16x16x32_bf16(pa1, LDB(1, 1, cc + 8), ghn, 0, 0, 0);
#undef LDB
#pragma unroll
            for (int rg = 0; rg < 4; ++rg) {
                int row = row0 + quad * 4 + rg;
                float pv = h_prev[(size_t)row * 64 + cc * 16 + l16];
                float rr = 1.f / (1.f + __expf(-(gir[rg] + bi[0][cc] + ghr[rg] + bh[0][cc])));
                float zz = 1.f / (1.f + __expf(-(giz[rg] + bi[1][cc] + ghz[rg] + bh[1][cc])));
                float nn = tanhf(gin[rg] + bi[2][cc] + rr * (ghn[rg] + bh[2][cc]));
                float hn = (1.f - zz) * nn + zz * pv;
                out_h[(size_t)row * 64 + cc * 16 + l16] = hn;
                p[rg][0] += hn * wv[cc][0];
                p[rg][1] += hn * wv[cc][1];
                p[rg][2] += hn * wv[cc][2];
            }
        }
#pragma unroll
        for (int rg = 0; rg < 4; ++rg) {
#pragma unroll
            for (int m = 1; m < 16; m <<= 1) {
                p[rg][0] += __shfl_xor(p[rg][0], m);
                p[rg][1] += __shfl_xor(p[rg][1], m);
                p[rg][2] += __shfl_xor(p[rg][2], m);
            }
        }
        if (l16 == 0) {
#pragma unroll
            for (int rg = 0; rg < 4; ++rg) {
                int row = row0 + quad * 4 + rg;
                out_o[(size_t)row * 3 + 0] = p[rg][0] + bro0;
                out_o[(size_t)row * 3 + 1] = p[rg][1] + bro1;
                out_o[(size_t)row * 3 + 2] = p[rg][2] + bro2;
            }
        }
    }
}

extern "C" void kernel_launch(void* const* d_in, const int* in_sizes, int n_in,
                              void* d_out, int out_size, void* d_ws, size_t ws_size,
                              hipStream_t stream) {
    const float* x        = (const float*)d_in[0];
    const float* h_prev   = (const float*)d_in[1];
    const int* node_idx   = (const int*)d_in[2];
    const int* hedge_idx  = (const int*)d_in[3];
    const int* edge_attr  = (const int*)d_in[4];
    const float* W_conv   = (const float*)d_in[5];
    const float* b_conv   = (const float*)d_in[6];
    const float* W_mix    = (const float*)d_in[7];
    const float* b_mix    = (const float*)d_in[8];
    const float* W_ih     = (const float*)d_in[9];
    const float* W_hh     = (const float*)d_in[10];
    const float* b_ih     = (const float*)d_in[11];
    const float* b_hh     = (const float*)d_in[12];
    const float* W_ro     = (const float*)d_in[13];
    const float* b_ro     = (const float*)d_in[14];

    char* p = (char*)d_ws;
    auto alloc = [&](size_t bytes) {
        char* r = p;
        p += (bytes + 63) & ~(size_t)63;
        return r;
    };
    int* cnt       = (int*)alloc((size_t)TOT * 4);        // [zeroed]
    int* off       = (int*)alloc((size_t)(TOT + 1) * 4);
    int* cursor    = (int*)alloc((size_t)TOT * 4);
    int* offT      = (int*)alloc((size_t)(MSEG + 1) * NSUB * 4);
    int* bsum      = (int*)alloc(1024 * 4);
    int* sortedAll = (int*)alloc((size_t)2 * N_EDGES * 4);
    bf16* xl       = (bf16*)alloc((size_t)2 * N_NODES * 64 * 2);
    bf16* ef16     = (bf16*)alloc((size_t)HSEG * 64 * 2);
    bf16* hbuf16   = (bf16*)alloc((size_t)N_NODES * 64 * 2);
    bf16* mixin16  = xl;  // alias: xl dead after k_ef2

    hipMemsetAsync(cnt, 0, (size_t)TOT * 4, stream);

    float* out_h = (float*)d_out;
    float* out_o = out_h + (size_t)N_NODES * 64;

    k_conv<<<512, 256, 0, stream>>>(x, W_conv, xl);
    k_hist<<<(N_EDGES + 255) / 256, 256, 0, stream>>>(node_idx, hedge_idx, edge_attr, cnt);
    k_scan1<<<SCAN_BLOCKS, 256, 0, stream>>>(cnt, off, bsum);
    k_scan2<<<1, 1024, 0, stream>>>(bsum);
    k_scan3<<<SCAN_BLOCKS, 256, 0, stream>>>(off, bsum, cursor, offT);
    k_scatter<<<(N_EDGES + 255) / 256, 256, 0, stream>>>(node_idx, hedge_idx, edge_attr,
                                                         cursor, sortedAll);
    k_ef2<<<HSEG / 16, 256, 0, stream>>>(offT, sortedAll, xl, ef16);
    k_no2<<<NSEG / 16, 256, 0, stream>>>(offT, sortedAll, ef16, b_conv, mixin16);
    k_mix<<<512, 256, 0, stream>>>(mixin16, W_mix, b_mix, hbuf16);
    k_gru<<<512, 256, 0, stream>>>(hbuf16, h_prev, W_ih, W_hh, b_ih, b_hh,
                                   W_ro, b_ro, out_h, out_o);
}